// Round 14
// baseline (1687.340 us; speedup 1.0000x reference)
//
#include <hip/hip_runtime.h>
#include <hip/hip_bf16.h>
#include <math.h>

#define B_ 32
#define S_ 64
#define T_ 64
#define V_ 32000
#define E_ 512
#define H_ 1024

typedef __attribute__((ext_vector_type(8))) short short8;
typedef __attribute__((ext_vector_type(4))) float f32x4;

static __device__ __forceinline__ unsigned short f2bf(float f) {
  union { float f; unsigned u; } c; c.f = f;
  unsigned r = (c.u + 0x7fffu + ((c.u >> 16) & 1u)) >> 16;  // RNE
  return (unsigned short)r;
}

// ---------- gather embedding rows (fp32, exact) ----------
__global__ __launch_bounds__(128)
void gather_f32(const int* __restrict__ idx, const float* __restrict__ emb,
                float* __restrict__ dst) {
  int r = blockIdx.x;
  int tid = threadIdx.x;
  int tok = idx[r];
  float4 v = *(const float4*)(emb + (size_t)tok * E_ + tid * 4);
  *(float4*)(dst + (size_t)r * E_ + tid * 4) = v;
}

// ---------- f64-accumulate GEMM: C[M,N](f32) = A[M,K](f32) @ B[K,N](f32) + bias ----------
// As padded to 68 (16B-aligned rows) -> b128 LDS reads. Accum order unchanged.
__global__ __launch_bounds__(256)
void dgemm_bias(const float* __restrict__ A, const float* __restrict__ B,
                const float* __restrict__ bias, float* __restrict__ C,
                int M, int N, int K) {
  __shared__ float As[32][68];  // [k][m], padded to 16B multiple
  __shared__ float Bs[32][64];  // [k][n]
  const int nbm = M >> 6;
  const int bm = blockIdx.x % nbm;
  const int bn = blockIdx.x / nbm;
  const int tid = threadIdx.x;
  const int tr = tid >> 4, tc = tid & 15;
  double acc[4][4] = {};

  for (int kt = 0; kt < K; kt += 32) {
    {
      int arow = tid >> 3, acol = (tid & 7) * 4;
#pragma unroll
      for (int p = 0; p < 2; ++p) {
        int r = arow + p * 32;
        float4 v = *(const float4*)(A + (size_t)(bm * 64 + r) * K + kt + acol);
        As[acol + 0][r] = v.x; As[acol + 1][r] = v.y;
        As[acol + 2][r] = v.z; As[acol + 3][r] = v.w;
      }
      int brow = tid >> 4, bcol = (tid & 15) * 4;
#pragma unroll
      for (int p = 0; p < 2; ++p) {
        int r = brow + p * 16;
        float4 v = *(const float4*)(B + (size_t)(kt + r) * N + bn * 64 + bcol);
        *(float4*)(&Bs[r][bcol]) = v;
      }
    }
    __syncthreads();
#pragma unroll
    for (int k = 0; k < 32; ++k) {
      float4 av = *(const float4*)(&As[k][tr * 4]);
      float4 bv = *(const float4*)(&Bs[k][tc * 4]);
      double a[4] = {(double)av.x, (double)av.y, (double)av.z, (double)av.w};
      double b[4] = {(double)bv.x, (double)bv.y, (double)bv.z, (double)bv.w};
#pragma unroll
      for (int i = 0; i < 4; ++i)
#pragma unroll
        for (int j = 0; j < 4; ++j) acc[i][j] = fma(a[i], b[j], acc[i][j]);
    }
    __syncthreads();
  }
#pragma unroll
  for (int i = 0; i < 4; ++i) {
    int gm = bm * 64 + tr * 4 + i;
    int gn = bn * 64 + tc * 4;
    float4 o;
    o.x = (float)(acc[i][0] + (double)bias[gn + 0]);
    o.y = (float)(acc[i][1] + (double)bias[gn + 1]);
    o.z = (float)(acc[i][2] + (double)bias[gn + 2]);
    o.w = (float)(acc[i][3] + (double)bias[gn + 3]);
    *(float4*)(C + (size_t)gm * N + gn) = o;
  }
}

// ---------- transpose fp32 [K][N] -> fp32 [N][K] ----------
__global__ __launch_bounds__(256)
void transpose_f32(const float* __restrict__ W, float* __restrict__ WT,
                   int K, int N) {
  __shared__ float t[64][65];
  int k0 = blockIdx.x * 64;
  int n0 = blockIdx.y * 64;
  int tid = threadIdx.x;
  int r = tid >> 4, c4 = tid & 15;
#pragma unroll
  for (int i = 0; i < 4; ++i) {
    int row = r + i * 16;
    float4 v = *(const float4*)(W + (size_t)(k0 + row) * N + n0 + c4 * 4);
    t[row][c4 * 4 + 0] = v.x; t[row][c4 * 4 + 1] = v.y;
    t[row][c4 * 4 + 2] = v.z; t[row][c4 * 4 + 3] = v.w;
  }
  __syncthreads();
#pragma unroll
  for (int i = 0; i < 4; ++i) {
    int n = r + i * 16;
    float4 o;
    o.x = t[c4 * 4 + 0][n]; o.y = t[c4 * 4 + 1][n];
    o.z = t[c4 * 4 + 2][n]; o.w = t[c4 * 4 + 3][n];
    *(float4*)(WT + (size_t)(n0 + n) * K + k0 + c4 * 4) = o;
  }
}

// ---------- transpose fp32 [K][N] -> bf16 [N][K] ----------
__global__ __launch_bounds__(256)
void transpose_bf16(const float* __restrict__ W, unsigned short* __restrict__ WT,
                    int K, int N) {
  __shared__ float t[64][65];
  int k0 = blockIdx.x * 64;
  int n0 = blockIdx.y * 64;
  int tid = threadIdx.x;
  int r = tid >> 4, c4 = tid & 15;
#pragma unroll
  for (int i = 0; i < 4; ++i) {
    int row = r + i * 16;
    float4 v = *(const float4*)(W + (size_t)(k0 + row) * N + n0 + c4 * 4);
    t[row][c4 * 4 + 0] = v.x; t[row][c4 * 4 + 1] = v.y;
    t[row][c4 * 4 + 2] = v.z; t[row][c4 * 4 + 3] = v.w;
  }
  __syncthreads();
#pragma unroll
  for (int i = 0; i < 4; ++i) {
    int n = r + i * 16;
    ushort4 o;
    o.x = f2bf(t[c4 * 4 + 0][n]); o.y = f2bf(t[c4 * 4 + 1][n]);
    o.z = f2bf(t[c4 * 4 + 2][n]); o.w = f2bf(t[c4 * 4 + 3][n]);
    *(ushort4*)(WT + (size_t)(n0 + n) * K + k0 + c4 * 4) = o;
  }
}

// ---------- bf16 MFMA GEMM: C[M,N] = A[M,K] * BT[N,K]^T + bias ----------
// 128x128 tile, reg-staged + XOR-swizzled LDS, XCD-aware block swizzle,
// NT C-stores (round-6 proven form).
__global__ __launch_bounds__(256)
void gemm_bt_swap(const unsigned short* __restrict__ A, const unsigned short* __restrict__ BT,
                  const float* __restrict__ bias, float* __restrict__ C,
                  int M, int N, int K) {
  __shared__ unsigned short As[128 * 64];
  __shared__ unsigned short Bs[128 * 64];
  const int nbm = M >> 7;
  int idx = blockIdx.x;
  const int cpx = gridDim.x >> 3;
  idx = (idx & 7) * cpx + (idx >> 3);
  const int bm = idx % nbm;
  const int bn = idx / nbm;
  const int tid = threadIdx.x;
  const int lane = tid & 63;
  const int wr = (tid >> 6) >> 1;
  const int wc = (tid >> 6) & 1;

  f32x4 acc[4][4] = {};

  for (int kt = 0; kt < K; kt += 64) {
#pragma unroll
    for (int i = 0; i < 4; ++i) {
      int c = i * 256 + tid;
      int row = c >> 3, col8 = c & 7;
      int sw = col8 ^ (row & 7);
      short8 av = *(const short8*)(A + (size_t)(bm * 128 + row) * K + kt + col8 * 8);
      short8 bv = *(const short8*)(BT + (size_t)(bn * 128 + row) * K + kt + col8 * 8);
      *(short8*)(As + row * 64 + sw * 8) = av;
      *(short8*)(Bs + row * 64 + sw * 8) = bv;
    }
    __syncthreads();
#pragma unroll
    for (int kk = 0; kk < 64; kk += 32) {
      int kc = (kk + ((lane >> 4) << 3)) >> 3;
      short8 af[4], bfr[4];
#pragma unroll
      for (int mi = 0; mi < 4; ++mi) {
        int row = wr * 64 + mi * 16 + (lane & 15);
        af[mi] = *(const short8*)(As + row * 64 + ((kc ^ (row & 7)) << 3));
      }
#pragma unroll
      for (int ni = 0; ni < 4; ++ni) {
        int row = wc * 64 + ni * 16 + (lane & 15);
        bfr[ni] = *(const short8*)(Bs + row * 64 + ((kc ^ (row & 7)) << 3));
      }
#pragma unroll
      for (int mi = 0; mi < 4; ++mi)
#pragma unroll
        for (int ni = 0; ni < 4; ++ni)
          acc[mi][ni] = __builtin_amdgcn_mfma_f32_16x16x32_bf16(
              af[mi], bfr[ni], acc[mi][ni], 0, 0, 0);
    }
    __syncthreads();
  }

  const int cq = (lane >> 4) << 2;
  const int cn = lane & 15;
#pragma unroll
  for (int mi = 0; mi < 4; ++mi) {
#pragma unroll
    for (int ni = 0; ni < 4; ++ni) {
      int gn = bn * 128 + wc * 64 + ni * 16 + cn;
      float bv = bias[gn];
#pragma unroll
      for (int q = 0; q < 4; ++q) {
        int gm = bm * 128 + wr * 64 + mi * 16 + cq + q;
        int b = gm & (B_ - 1);
        int t = gm >> 5;
        __builtin_nontemporal_store(acc[mi][ni][q] + bv,
                                    &C[((size_t)b * T_ + t) * N + gn]);
      }
    }
  }
}

// ---------- persistent scan, 2 co-resident blocks/CU from DIFFERENT chains ----------
// Grid 512 = 8 groups x 64 blocks (16 j-cols each). grp = (blockIdx&7)^(blockIdx>>8):
// cohabiting blocks (i, i+256) and neighbors (i, i+1) are different groups, so one
// block's barrier-poll stall hides under the other's FMA (TLP, not phasing — r11/r13
// failed with explicit interleave). __launch_bounds__(512,4) caps VGPR<=128 to
// guarantee 2-block/CU co-residency (all 512 blocks resident -> no deadlock).
// Per-step body verbatim r12 (proven); reduction now 8 accs / 10 f64 shfls (f64
// reorder is trajectory-exact, r3/r13). hsb HBM store moved AFTER the signal so
// its ack rides under next step's staging instead of the pre-signal vmcnt(0).
__global__ __launch_bounds__(512, 4)
void rnn_scan_split(const float* __restrict__ xe, const float* __restrict__ xd,
                    const float* __restrict__ WTe, const float* __restrict__ WTd,
                    const float* __restrict__ bhhE, const float* __restrict__ bhhD,
                    float* __restrict__ hA, float* __restrict__ hB,
                    unsigned short* __restrict__ hsb, unsigned* __restrict__ bar) {
  __shared__ float hl[4 * 1024];  // 16 KB chain h-slice
  const int tid = threadIdx.x;
  const int half = blockIdx.x >> 8;                 // 0 | 1
  const int grp = (blockIdx.x & 7) ^ half;          // chain group 0..7
  const int jslot = ((blockIdx.x >> 3) & 31) + (half << 5);  // 0..63
  const int jbase = jslot * 16;
  const int bg = grp * 4;
  const int w = tid >> 6;  // wave -> j-pair
  const int l = tid & 63;  // k-split lane
  unsigned* mybar = bar + grp * 32;  // 128B-spaced counters

  // final-owner mapping for 8-acc pair-swap reduction: a = 4b0 + 2b1 + b2
  const int a = 4 * (l & 1) + 2 * ((l >> 1) & 1) + ((l >> 2) & 1);
  const int lb = a >> 1;           // local batch 0..3
  const int gb = bg + lb;
  const int gj = jbase + w * 2 + (a & 1);
  const float bje = bhhE[gj];
  const float bjd = bhhD[gj];

  // W fragments in registers (2 j-cols per wave)
  float4 wreg[4][2];
  {
    const float* wsrc = WTe + (size_t)(jbase + w * 2) * 1024;
#pragma unroll
    for (int i = 0; i < 4; ++i) {
      int g = l + 64 * i;
#pragma unroll
      for (int ji = 0; ji < 2; ++ji)
        wreg[i][ji] = *(const float4*)(wsrc + (size_t)ji * 1024 + g * 4);
    }
  }

  for (int t = 0; t < 128; ++t) {
    if (t == 64) {  // decoder weights (one-time reload)
      const float* wsrc = WTd + (size_t)(jbase + w * 2) * 1024;
#pragma unroll
      for (int i = 0; i < 4; ++i) {
        int g = l + 64 * i;
#pragma unroll
        for (int ji = 0; ji < 2; ++ji)
          wreg[i][ji] = *(const float4*)(wsrc + (size_t)ji * 1024 + g * 4);
      }
    }
    const bool enc = (t < 64);
    const int s = t & 63;
    const float* __restrict__ h_in = (t & 1) ? hB : hA;
    float* __restrict__ h_out = (t & 1) ? hA : hB;
    const float* __restrict__ x = enc ? xe : xd;

    float xv = x[((size_t)gb * 64 + s) * H_ + gj];  // overlaps staging

    // stage chain h-slice: lane-consecutive (coalesced + conflict-free, r12)
    {
      const float* hsrc = h_in + bg * H_;
      float v[8];
#pragma unroll
      for (int u = 0; u < 8; ++u)
        v[u] = __hip_atomic_load(hsrc + u * 512 + tid, __ATOMIC_RELAXED,
                                 __HIP_MEMORY_SCOPE_AGENT);
#pragma unroll
      for (int u = 0; u < 8; ++u)
        hl[u * 512 + tid] = v[u];
    }
    __syncthreads();

    double acc[4][2];
#pragma unroll
    for (int bi = 0; bi < 4; ++bi)
#pragma unroll
      for (int ji = 0; ji < 2; ++ji) acc[bi][ji] = 0.;

#pragma unroll
    for (int i = 0; i < 4; ++i) {
      int g = l + 64 * i;
      float4 hv[4];
#pragma unroll
      for (int bi = 0; bi < 4; ++bi)
        hv[bi] = *(const float4*)(hl + bi * 1024 + g * 4);
#pragma unroll
      for (int bi = 0; bi < 4; ++bi)
#pragma unroll
        for (int ji = 0; ji < 2; ++ji) {
          acc[bi][ji] = fma((double)hv[bi].x, (double)wreg[i][ji].x, acc[bi][ji]);
          acc[bi][ji] = fma((double)hv[bi].y, (double)wreg[i][ji].y, acc[bi][ji]);
          acc[bi][ji] = fma((double)hv[bi].z, (double)wreg[i][ji].z, acc[bi][ji]);
          acc[bi][ji] = fma((double)hv[bi].w, (double)wreg[i][ji].w, acc[bi][ji]);
        }
    }

    // acc-halving pair-swap reduction: flat af(a) = acc[a>>1][a&1], 10 f64 shfls
    double r4_[4], r2_[2], r1;
#pragma unroll
    for (int aa = 0; aa < 4; ++aa) {
      double lo = acc[aa >> 1][aa & 1];
      double hi = acc[(aa + 4) >> 1][(aa + 4) & 1];
      double send = (l & 1) ? lo : hi;
      double mine = (l & 1) ? hi : lo;
      r4_[aa] = mine + __shfl_xor(send, 1);
    }
#pragma unroll
    for (int aa = 0; aa < 2; ++aa) {
      double send = (l & 2) ? r4_[aa] : r4_[aa + 2];
      double mine = (l & 2) ? r4_[aa + 2] : r4_[aa];
      r2_[aa] = mine + __shfl_xor(send, 2);
    }
    {
      double send = (l & 4) ? r2_[0] : r2_[1];
      double mine = (l & 4) ? r2_[1] : r2_[0];
      r1 = mine + __shfl_xor(send, 4);
    }
    r1 += __shfl_xor(r1, 8);
    r1 += __shfl_xor(r1, 16);
    r1 += __shfl_xor(r1, 32);

    float hf = 0.f;
    if (l < 8) {
      double vv = r1 + (double)xv + (double)(enc ? bje : bjd);
      double h = tanh(vv);
      hf = (float)h;
      __hip_atomic_store(&h_out[(size_t)gb * H_ + gj], hf, __ATOMIC_RELAXED,
                         __HIP_MEMORY_SCOPE_AGENT);
    }

    // ---- group barrier: relaxed atomics only (no L2 flush) ----
    if (t < 127) {
      asm volatile("s_waitcnt vmcnt(0)" ::: "memory");  // h stores ack'd
      __syncthreads();
      if (tid == 0) {
        __hip_atomic_fetch_add(mybar, 1u, __ATOMIC_RELAXED,
                               __HIP_MEMORY_SCOPE_AGENT);
        unsigned tgt = 64u * (unsigned)(t + 1);
        while (__hip_atomic_load(mybar, __ATOMIC_RELAXED,
                                 __HIP_MEMORY_SCOPE_AGENT) < tgt)
          __builtin_amdgcn_s_sleep(1);
      }
      __syncthreads();
    }
    // hsb store AFTER the signal: its HBM ack overlaps next step's staging
    if (!enc && l < 8)
      __builtin_nontemporal_store(f2bf(hf),
                                  &hsb[(size_t)s * (B_ * H_) + (size_t)gb * H_ + gj]);
  }
}

// ---------- log-softmax, row staged in LDS (one HBM read + one write) ----------
__global__ __launch_bounds__(512)
void log_softmax_rows(float* __restrict__ out) {
  __shared__ float rl[32000];  // 125 KB row stage
  __shared__ float wm[8], wsv[8];
  float* row = out + (size_t)blockIdx.x * V_;
  const int tid = threadIdx.x;
  float m = -INFINITY, s = 0.f;
  for (int i = tid; i < V_ / 4; i += 512) {
    float4 v = *(const float4*)(row + i * 4);
    *(float4*)(rl + i * 4) = v;
    float mx = fmaxf(fmaxf(v.x, v.y), fmaxf(v.z, v.w));
    if (mx > m) { s *= __expf(m - mx); m = mx; }
    s += __expf(v.x - m) + __expf(v.y - m) + __expf(v.z - m) + __expf(v.w - m);
  }
#pragma unroll
  for (int o = 32; o; o >>= 1) {
    float mo = __shfl_xor(m, o);
    float so = __shfl_xor(s, o);
    float mn = fmaxf(m, mo);
    s = s * __expf(m - mn) + so * __expf(mo - mn);
    m = mn;
  }
  int wv = tid >> 6;
  if ((tid & 63) == 0) { wm[wv] = m; wsv[wv] = s; }
  __syncthreads();
  float M = wm[0];
#pragma unroll
  for (int i = 1; i < 8; ++i) M = fmaxf(M, wm[i]);
  float Ssum = 0.f;
#pragma unroll
  for (int i = 0; i < 8; ++i) Ssum += wsv[i] * __expf(wm[i] - M);
  float L = M + logf(Ssum);
  for (int i = tid; i < V_ / 4; i += 512) {
    float4 v = *(const float4*)(rl + i * 4);
    v.x -= L; v.y -= L; v.z -= L; v.w -= L;
    __builtin_nontemporal_store(v.x, &row[i * 4 + 0]);
    __builtin_nontemporal_store(v.y, &row[i * 4 + 1]);
    __builtin_nontemporal_store(v.z, &row[i * 4 + 2]);
    __builtin_nontemporal_store(v.w, &row[i * 4 + 3]);
  }
}

extern "C" void kernel_launch(void* const* d_in, const int* in_sizes, int n_in,
                              void* d_out, int out_size, void* d_ws, size_t ws_size,
                              hipStream_t stream) {
  const int*   src  = (const int*)  d_in[0];
  const int*   tgt  = (const int*)  d_in[1];
  const float* encE = (const float*)d_in[2];
  const float* decE = (const float*)d_in[3];
  const float* WihE = (const float*)d_in[4];
  const float* bihE = (const float*)d_in[5];
  const float* WhhE = (const float*)d_in[6];
  const float* bhhE = (const float*)d_in[7];
  const float* WihD = (const float*)d_in[8];
  const float* bihD = (const float*)d_in[9];
  const float* WhhD = (const float*)d_in[10];
  const float* bhhD = (const float*)d_in[11];
  const float* Wout = (const float*)d_in[12];
  const float* bout = (const float*)d_in[13];
  float* out = (float*)d_out;

  char* w = (char*)d_ws;
  float* x_e = (float*)w;                      w += (size_t)2048 * 1024 * 4;
  float* x_d = (float*)w;                      w += (size_t)2048 * 1024 * 4;
  float* h0  = (float*)w;                      w += 32 * 1024 * 4;
  float* h1  = (float*)w;                      w += 32 * 1024 * 4;
  unsigned* bar = (unsigned*)w;                w += 8 * 32 * 4;  // 8 counters, 128B apart
  float* WhhTe = (float*)w;                    w += (size_t)1024 * 1024 * 4;
  float* WhhTd = (float*)w;                    w += (size_t)1024 * 1024 * 4;
  float* AembF = (float*)w;                    w += (size_t)2048 * 512 * 4;
  unsigned short* hsb   = (unsigned short*)w;  w += (size_t)2048 * 1024 * 2;
  unsigned short* WoutT = (unsigned short*)w;  w += (size_t)V_ * 1024 * 2;

  // Input projections (f64-exact accumulate, f32 storage)
  gather_f32<<<B_ * S_, 128, 0, stream>>>(src, encE, AembF);
  dgemm_bias<<<(2048 / 64) * (H_ / 64), 256, 0, stream>>>(AembF, WihE, bihE, x_e,
                                                          2048, H_, E_);
  gather_f32<<<B_ * T_, 128, 0, stream>>>(tgt, decE, AembF);
  dgemm_bias<<<(2048 / 64) * (H_ / 64), 256, 0, stream>>>(AembF, WihD, bihD, x_d,
                                                          2048, H_, E_);

  // Pre-transpose recurrence weights: WhhT[j][k]
  transpose_f32<<<dim3(H_ / 64, H_ / 64), 256, 0, stream>>>(WhhE, WhhTe, H_, H_);
  transpose_f32<<<dim3(H_ / 64, H_ / 64), 256, 0, stream>>>(WhhD, WhhTd, H_, H_);

  // Persistent scan: 512 blocks, 2/CU from different chains (TLP latency hiding)
  hipMemsetAsync(h0, 0, 32 * 1024 * 4, stream);
  hipMemsetAsync(bar, 0, 8 * 32 * 4, stream);
  rnn_scan_split<<<512, 512, 0, stream>>>(x_e, x_d, WhhTe, WhhTd, bhhE, bhhD,
                                          h0, h1, hsb, bar);

  // Logits: out[b][t][:] = hs[t*B+b] @ Wout + bout  (bf16 MFMA, raw logits)
  transpose_bf16<<<dim3(H_ / 64, V_ / 64), 256, 0, stream>>>(Wout, WoutT, H_, V_);
  gemm_bt_swap<<<(2048 / 128) * (V_ / 128), 256, 0, stream>>>(hsb, WoutT, bout, out,
                                                              2048, V_, H_);
  // In-place log-softmax
  log_softmax_rows<<<B_ * T_, 512, 0, stream>>>(out);
}

// Round 16
// 1021.649 us; speedup vs baseline: 1.6516x; 1.6516x over previous
//
#include <hip/hip_runtime.h>
#include <hip/hip_bf16.h>
#include <math.h>

#define B_ 32
#define S_ 64
#define T_ 64
#define V_ 32000
#define E_ 512
#define H_ 1024

typedef __attribute__((ext_vector_type(8))) short short8;
typedef __attribute__((ext_vector_type(4))) float f32x4;

static __device__ __forceinline__ unsigned short f2bf(float f) {
  union { float f; unsigned u; } c; c.f = f;
  unsigned r = (c.u + 0x7fffu + ((c.u >> 16) & 1u)) >> 16;  // RNE
  return (unsigned short)r;
}

// ---------- fused embed + f64-accumulate GEMM ----------
// C[M,N](f32) = emb[idx[m]][:] @ B[K,N](f32) + bias, K = E_ = 512.
// Staging/accumulation order identical to r12's dgemm_bias (A values are the
// same floats, gathered inline) -> bit-identical x.
__global__ __launch_bounds__(256)
void dgemm_embed(const int* __restrict__ idx, const float* __restrict__ emb,
                 const float* __restrict__ B, const float* __restrict__ bias,
                 float* __restrict__ C, int M, int N, int K) {
  __shared__ float As[32][68];  // [k][m], padded to 16B multiple
  __shared__ float Bs[32][64];  // [k][n]
  const int nbm = M >> 6;
  const int bm = blockIdx.x % nbm;
  const int bn = blockIdx.x / nbm;
  const int tid = threadIdx.x;
  const int tr = tid >> 4, tc = tid & 15;

  // hoist token row pointers (independent of kt)
  const int arow = tid >> 3, acol = (tid & 7) * 4;
  const float* arp[2];
#pragma unroll
  for (int p = 0; p < 2; ++p) {
    int r = arow + p * 32;
    arp[p] = emb + (size_t)idx[bm * 64 + r] * E_;
  }

  double acc[4][4] = {};

  for (int kt = 0; kt < K; kt += 32) {
    {
#pragma unroll
      for (int p = 0; p < 2; ++p) {
        int r = arow + p * 32;
        float4 v = *(const float4*)(arp[p] + kt + acol);
        As[acol + 0][r] = v.x; As[acol + 1][r] = v.y;
        As[acol + 2][r] = v.z; As[acol + 3][r] = v.w;
      }
      int brow = tid >> 4, bcol = (tid & 15) * 4;
#pragma unroll
      for (int p = 0; p < 2; ++p) {
        int r = brow + p * 16;
        float4 v = *(const float4*)(B + (size_t)(kt + r) * N + bn * 64 + bcol);
        *(float4*)(&Bs[r][bcol]) = v;
      }
    }
    __syncthreads();
#pragma unroll
    for (int k = 0; k < 32; ++k) {
      float4 av = *(const float4*)(&As[k][tr * 4]);
      float4 bv = *(const float4*)(&Bs[k][tc * 4]);
      double a[4] = {(double)av.x, (double)av.y, (double)av.z, (double)av.w};
      double b[4] = {(double)bv.x, (double)bv.y, (double)bv.z, (double)bv.w};
#pragma unroll
      for (int i = 0; i < 4; ++i)
#pragma unroll
        for (int j = 0; j < 4; ++j) acc[i][j] = fma(a[i], b[j], acc[i][j]);
    }
    __syncthreads();
  }
#pragma unroll
  for (int i = 0; i < 4; ++i) {
    int gm = bm * 64 + tr * 4 + i;
    int gn = bn * 64 + tc * 4;
    float4 o;
    o.x = (float)(acc[i][0] + (double)bias[gn + 0]);
    o.y = (float)(acc[i][1] + (double)bias[gn + 1]);
    o.z = (float)(acc[i][2] + (double)bias[gn + 2]);
    o.w = (float)(acc[i][3] + (double)bias[gn + 3]);
    *(float4*)(C + (size_t)gm * N + gn) = o;
  }
}

// ---------- transpose fp32 [K][N] -> fp32 [N][K] ----------
__global__ __launch_bounds__(256)
void transpose_f32(const float* __restrict__ W, float* __restrict__ WT,
                   int K, int N) {
  __shared__ float t[64][65];
  int k0 = blockIdx.x * 64;
  int n0 = blockIdx.y * 64;
  int tid = threadIdx.x;
  int r = tid >> 4, c4 = tid & 15;
#pragma unroll
  for (int i = 0; i < 4; ++i) {
    int row = r + i * 16;
    float4 v = *(const float4*)(W + (size_t)(k0 + row) * N + n0 + c4 * 4);
    t[row][c4 * 4 + 0] = v.x; t[row][c4 * 4 + 1] = v.y;
    t[row][c4 * 4 + 2] = v.z; t[row][c4 * 4 + 3] = v.w;
  }
  __syncthreads();
#pragma unroll
  for (int i = 0; i < 4; ++i) {
    int n = r + i * 16;
    float4 o;
    o.x = t[c4 * 4 + 0][n]; o.y = t[c4 * 4 + 1][n];
    o.z = t[c4 * 4 + 2][n]; o.w = t[c4 * 4 + 3][n];
    *(float4*)(WT + (size_t)(n0 + n) * K + k0 + c4 * 4) = o;
  }
}

// ---------- transpose fp32 [K][N] -> bf16 [N][K] ----------
__global__ __launch_bounds__(256)
void transpose_bf16(const float* __restrict__ W, unsigned short* __restrict__ WT,
                    int K, int N) {
  __shared__ float t[64][65];
  int k0 = blockIdx.x * 64;
  int n0 = blockIdx.y * 64;
  int tid = threadIdx.x;
  int r = tid >> 4, c4 = tid & 15;
#pragma unroll
  for (int i = 0; i < 4; ++i) {
    int row = r + i * 16;
    float4 v = *(const float4*)(W + (size_t)(k0 + row) * N + n0 + c4 * 4);
    t[row][c4 * 4 + 0] = v.x; t[row][c4 * 4 + 1] = v.y;
    t[row][c4 * 4 + 2] = v.z; t[row][c4 * 4 + 3] = v.w;
  }
  __syncthreads();
#pragma unroll
  for (int i = 0; i < 4; ++i) {
    int n = r + i * 16;
    ushort4 o;
    o.x = f2bf(t[c4 * 4 + 0][n]); o.y = f2bf(t[c4 * 4 + 1][n]);
    o.z = f2bf(t[c4 * 4 + 2][n]); o.w = f2bf(t[c4 * 4 + 3][n]);
    *(ushort4*)(WT + (size_t)(n0 + n) * K + k0 + c4 * 4) = o;
  }
}

// ---------- bf16 MFMA GEMM: C[M,N] = A[M,K] * BT[N,K]^T + bias ----------
// 128x128 tile, XOR-swizzled LDS, XCD swizzle, NT C-stores (r6 proven) +
// T14 reg-prefetch split: tile k+1's global loads issue under tile k's MFMAs.
__global__ __launch_bounds__(256)
void gemm_bt_swap(const unsigned short* __restrict__ A, const unsigned short* __restrict__ BT,
                  const float* __restrict__ bias, float* __restrict__ C,
                  int M, int N, int K) {
  __shared__ unsigned short As[128 * 64];
  __shared__ unsigned short Bs[128 * 64];
  const int nbm = M >> 7;
  int idx = blockIdx.x;
  const int cpx = gridDim.x >> 3;
  idx = (idx & 7) * cpx + (idx >> 3);
  const int bm = idx % nbm;
  const int bn = idx / nbm;
  const int tid = threadIdx.x;
  const int lane = tid & 63;
  const int wr = (tid >> 6) >> 1;
  const int wc = (tid >> 6) & 1;

  f32x4 acc[4][4] = {};

  // staging geometry (constant per thread)
  int srow[4], scol8[4], ssw[4];
#pragma unroll
  for (int i = 0; i < 4; ++i) {
    int c = i * 256 + tid;
    srow[i] = c >> 3; scol8[i] = c & 7;
    ssw[i] = scol8[i] ^ (srow[i] & 7);
  }

  // prologue: load tile 0 into regs
  short8 av[4], bv[4];
#pragma unroll
  for (int i = 0; i < 4; ++i) {
    av[i] = *(const short8*)(A + (size_t)(bm * 128 + srow[i]) * K + scol8[i] * 8);
    bv[i] = *(const short8*)(BT + (size_t)(bn * 128 + srow[i]) * K + scol8[i] * 8);
  }

  for (int kt = 0; kt < K; kt += 64) {
    // write current regs -> LDS
#pragma unroll
    for (int i = 0; i < 4; ++i) {
      *(short8*)(As + srow[i] * 64 + ssw[i] * 8) = av[i];
      *(short8*)(Bs + srow[i] * 64 + ssw[i] * 8) = bv[i];
    }
    __syncthreads();

    // prefetch next tile (overlaps the MFMA loop below)
    if (kt + 64 < K) {
#pragma unroll
      for (int i = 0; i < 4; ++i) {
        av[i] = *(const short8*)(A + (size_t)(bm * 128 + srow[i]) * K + kt + 64 + scol8[i] * 8);
        bv[i] = *(const short8*)(BT + (size_t)(bn * 128 + srow[i]) * K + kt + 64 + scol8[i] * 8);
      }
    }

#pragma unroll
    for (int kk = 0; kk < 64; kk += 32) {
      int kc = (kk + ((lane >> 4) << 3)) >> 3;
      short8 af[4], bfr[4];
#pragma unroll
      for (int mi = 0; mi < 4; ++mi) {
        int row = wr * 64 + mi * 16 + (lane & 15);
        af[mi] = *(const short8*)(As + row * 64 + ((kc ^ (row & 7)) << 3));
      }
#pragma unroll
      for (int ni = 0; ni < 4; ++ni) {
        int row = wc * 64 + ni * 16 + (lane & 15);
        bfr[ni] = *(const short8*)(Bs + row * 64 + ((kc ^ (row & 7)) << 3));
      }
#pragma unroll
      for (int mi = 0; mi < 4; ++mi)
#pragma unroll
        for (int ni = 0; ni < 4; ++ni)
          acc[mi][ni] = __builtin_amdgcn_mfma_f32_16x16x32_bf16(
              af[mi], bfr[ni], acc[mi][ni], 0, 0, 0);
    }
    __syncthreads();
  }

  const int cq = (lane >> 4) << 2;
  const int cn = lane & 15;
#pragma unroll
  for (int mi = 0; mi < 4; ++mi) {
#pragma unroll
    for (int ni = 0; ni < 4; ++ni) {
      int gn = bn * 128 + wc * 64 + ni * 16 + cn;
      float bvv = bias[gn];
#pragma unroll
      for (int q = 0; q < 4; ++q) {
        int gm = bm * 128 + wr * 64 + mi * 16 + cq + q;
        int b = gm & (B_ - 1);
        int t = gm >> 5;
        __builtin_nontemporal_store(acc[mi][ni][q] + bvv,
                                    &C[((size_t)b * T_ + t) * N + gn]);
      }
    }
  }
}

// ---------- persistent group-local RNN scan (r12 proven form) ----------
// 8 independent 4-batch chains (group = blockIdx&7), 32 blocks/chain.
// W fragments in registers (reload at t=64). Lane-consecutive coalesced
// staging (r12). Group barrier: relaxed agent atomic counter + tid0 poll.
// Only change vs r12: decoder hsb NT-store moved AFTER the barrier so its
// HBM ack is off the pre-signal vmcnt(0) critical path (ordering-safe:
// hsb is read only after kernel end).
__global__ __launch_bounds__(512)
void rnn_scan_grp2(const float* __restrict__ xe, const float* __restrict__ xd,
                   const float* __restrict__ WTe, const float* __restrict__ WTd,
                   const float* __restrict__ bhhE, const float* __restrict__ bhhD,
                   float* __restrict__ hA, float* __restrict__ hB,
                   unsigned short* __restrict__ hsb, unsigned* __restrict__ bar) {
  __shared__ float hl[4 * 1024];  // 16 KB chain h-slice
  const int tid = threadIdx.x;
  const int grp = blockIdx.x & 7;
  const int jslot = blockIdx.x >> 3;
  const int jbase = jslot * 32;
  const int bg = grp * 4;
  const int w = tid >> 6;  // wave -> j-quad
  const int l = tid & 63;  // k-split lane
  unsigned* mybar = bar + grp * 32;  // 128B-spaced counters

  // final-owner mapping (pair-swap reduction, proven r6)
  const int a = 8 * (l & 1) + 4 * ((l >> 1) & 1) + 2 * ((l >> 2) & 1) +
                ((l >> 3) & 1);
  const int lb = a >> 2;
  const int gb = bg + lb;
  const int gj = jbase + w * 4 + (a & 3);
  const float bje = bhhE[gj];
  const float bjd = bhhD[gj];

  // W fragments in registers
  float4 wreg[4][4];
  {
    const float* wsrc = WTe + (size_t)(jbase + w * 4) * 1024;
#pragma unroll
    for (int i = 0; i < 4; ++i) {
      int g = l + 64 * i;
#pragma unroll
      for (int ji = 0; ji < 4; ++ji)
        wreg[i][ji] = *(const float4*)(wsrc + (size_t)ji * 1024 + g * 4);
    }
  }

  for (int t = 0; t < 128; ++t) {
    if (t == 64) {  // decoder weights (one-time reload)
      const float* wsrc = WTd + (size_t)(jbase + w * 4) * 1024;
#pragma unroll
      for (int i = 0; i < 4; ++i) {
        int g = l + 64 * i;
#pragma unroll
        for (int ji = 0; ji < 4; ++ji)
          wreg[i][ji] = *(const float4*)(wsrc + (size_t)ji * 1024 + g * 4);
      }
    }
    const bool enc = (t < 64);
    const int s = t & 63;
    const float* __restrict__ h_in = (t & 1) ? hB : hA;
    float* __restrict__ h_out = (t & 1) ? hA : hB;
    const float* __restrict__ x = enc ? xe : xd;

    float xv = x[((size_t)gb * 64 + s) * H_ + gj];  // overlaps staging

    // stage chain h-slice: lane-consecutive (coalesced + conflict-free)
    {
      const float* hsrc = h_in + bg * H_;
      float v[8];
#pragma unroll
      for (int u = 0; u < 8; ++u)
        v[u] = __hip_atomic_load(hsrc + u * 512 + tid, __ATOMIC_RELAXED,
                                 __HIP_MEMORY_SCOPE_AGENT);
#pragma unroll
      for (int u = 0; u < 8; ++u)
        hl[u * 512 + tid] = v[u];
    }
    __syncthreads();

    double acc[4][4];
#pragma unroll
    for (int bi = 0; bi < 4; ++bi)
#pragma unroll
      for (int ji = 0; ji < 4; ++ji) acc[bi][ji] = 0.;

#pragma unroll
    for (int i = 0; i < 4; ++i) {
      int g = l + 64 * i;
      float4 hv[4];
#pragma unroll
      for (int bi = 0; bi < 4; ++bi)
        hv[bi] = *(const float4*)(hl + bi * 1024 + g * 4);
#pragma unroll
      for (int bi = 0; bi < 4; ++bi)
#pragma unroll
        for (int ji = 0; ji < 4; ++ji) {
          acc[bi][ji] = fma((double)hv[bi].x, (double)wreg[i][ji].x, acc[bi][ji]);
          acc[bi][ji] = fma((double)hv[bi].y, (double)wreg[i][ji].y, acc[bi][ji]);
          acc[bi][ji] = fma((double)hv[bi].z, (double)wreg[i][ji].z, acc[bi][ji]);
          acc[bi][ji] = fma((double)hv[bi].w, (double)wreg[i][ji].w, acc[bi][ji]);
        }
    }

    // acc-halving pair-swap reduction (17 f64 shfls; verbatim r6)
    double r8[8], r4[4], r2[2], r1;
#pragma unroll
    for (int aa = 0; aa < 8; ++aa) {
      double send = (l & 1) ? acc[aa >> 2][aa & 3] : acc[(aa + 8) >> 2][(aa + 8) & 3];
      double mine = (l & 1) ? acc[(aa + 8) >> 2][(aa + 8) & 3] : acc[aa >> 2][aa & 3];
      r8[aa] = mine + __shfl_xor(send, 1);
    }
#pragma unroll
    for (int aa = 0; aa < 4; ++aa) {
      double send = (l & 2) ? r8[aa] : r8[aa + 4];
      double mine = (l & 2) ? r8[aa + 4] : r8[aa];
      r4[aa] = mine + __shfl_xor(send, 2);
    }
#pragma unroll
    for (int aa = 0; aa < 2; ++aa) {
      double send = (l & 4) ? r4[aa] : r4[aa + 2];
      double mine = (l & 4) ? r4[aa + 2] : r4[aa];
      r2[aa] = mine + __shfl_xor(send, 4);
    }
    {
      double send = (l & 8) ? r2[0] : r2[1];
      double mine = (l & 8) ? r2[1] : r2[0];
      r1 = mine + __shfl_xor(send, 8);
    }
    r1 += __shfl_xor(r1, 16);
    r1 += __shfl_xor(r1, 32);

    float hf = 0.f;
    if (l < 16) {
      double v = r1 + (double)xv + (double)(enc ? bje : bjd);
      double h = tanh(v);
      hf = (float)h;
      __hip_atomic_store(&h_out[(size_t)gb * H_ + gj], hf, __ATOMIC_RELAXED,
                         __HIP_MEMORY_SCOPE_AGENT);
    }

    // ---- group barrier: relaxed atomics only (no L2 flush) ----
    if (t < 127) {
      asm volatile("s_waitcnt vmcnt(0)" ::: "memory");  // h stores ack'd
      __syncthreads();
      if (tid == 0) {
        __hip_atomic_fetch_add(mybar, 1u, __ATOMIC_RELAXED,
                               __HIP_MEMORY_SCOPE_AGENT);
        unsigned tgt = 32u * (unsigned)(t + 1);
        while (__hip_atomic_load(mybar, __ATOMIC_RELAXED,
                                 __HIP_MEMORY_SCOPE_AGENT) < tgt)
          __builtin_amdgcn_s_sleep(1);
      }
      __syncthreads();
    }
    // hsb NT-store AFTER the signal: its ack overlaps next step's staging
    if (!enc && l < 16)
      __builtin_nontemporal_store(f2bf(hf),
                                  &hsb[(size_t)s * (B_ * H_) + (size_t)gb * H_ + gj]);
  }
}

// ---------- log-softmax, row staged in LDS (one HBM read + one write) ----------
__global__ __launch_bounds__(1024)
void log_softmax_rows(float* __restrict__ out) {
  __shared__ float rl[32000];  // 125 KB row stage
  __shared__ float wm[16], wsv[16];
  float* row = out + (size_t)blockIdx.x * V_;
  const int tid = threadIdx.x;
  float m = -INFINITY, s = 0.f;
  for (int i = tid; i < V_ / 4; i += 1024) {
    float4 v = *(const float4*)(row + i * 4);
    *(float4*)(rl + i * 4) = v;
    float mx = fmaxf(fmaxf(v.x, v.y), fmaxf(v.z, v.w));
    if (mx > m) { s *= __expf(m - mx); m = mx; }
    s += __expf(v.x - m) + __expf(v.y - m) + __expf(v.z - m) + __expf(v.w - m);
  }
#pragma unroll
  for (int o = 32; o; o >>= 1) {
    float mo = __shfl_xor(m, o);
    float so = __shfl_xor(s, o);
    float mn = fmaxf(m, mo);
    s = s * __expf(m - mn) + so * __expf(mo - mn);
    m = mn;
  }
  int wv = tid >> 6;
  if ((tid & 63) == 0) { wm[wv] = m; wsv[wv] = s; }
  __syncthreads();
  float M = wm[0];
#pragma unroll
  for (int i = 1; i < 16; ++i) M = fmaxf(M, wm[i]);
  float Ssum = 0.f;
#pragma unroll
  for (int i = 0; i < 16; ++i) Ssum += wsv[i] * __expf(wm[i] - M);
  float L = M + logf(Ssum);
  for (int i = tid; i < V_ / 4; i += 1024) {
    float4 v = *(const float4*)(rl + i * 4);
    v.x -= L; v.y -= L; v.z -= L; v.w -= L;
    __builtin_nontemporal_store(v.x, &row[i * 4 + 0]);
    __builtin_nontemporal_store(v.y, &row[i * 4 + 1]);
    __builtin_nontemporal_store(v.z, &row[i * 4 + 2]);
    __builtin_nontemporal_store(v.w, &row[i * 4 + 3]);
  }
}

extern "C" void kernel_launch(void* const* d_in, const int* in_sizes, int n_in,
                              void* d_out, int out_size, void* d_ws, size_t ws_size,
                              hipStream_t stream) {
  const int*   src  = (const int*)  d_in[0];
  const int*   tgt  = (const int*)  d_in[1];
  const float* encE = (const float*)d_in[2];
  const float* decE = (const float*)d_in[3];
  const float* WihE = (const float*)d_in[4];
  const float* bihE = (const float*)d_in[5];
  const float* WhhE = (const float*)d_in[6];
  const float* bhhE = (const float*)d_in[7];
  const float* WihD = (const float*)d_in[8];
  const float* bihD = (const float*)d_in[9];
  const float* WhhD = (const float*)d_in[10];
  const float* bhhD = (const float*)d_in[11];
  const float* Wout = (const float*)d_in[12];
  const float* bout = (const float*)d_in[13];
  float* out = (float*)d_out;

  char* w = (char*)d_ws;
  float* x_e = (float*)w;                      w += (size_t)2048 * 1024 * 4;
  float* x_d = (float*)w;                      w += (size_t)2048 * 1024 * 4;
  float* h0  = (float*)w;                      w += 32 * 1024 * 4;
  float* h1  = (float*)w;                      w += 32 * 1024 * 4;
  unsigned* bar = (unsigned*)w;                w += 8 * 32 * 4;  // 8 counters, 128B apart
  float* WhhTe = (float*)w;                    w += (size_t)1024 * 1024 * 4;
  float* WhhTd = (float*)w;                    w += (size_t)1024 * 1024 * 4;
  unsigned short* hsb   = (unsigned short*)w;  w += (size_t)2048 * 1024 * 2;
  unsigned short* WoutT = (unsigned short*)w;  w += (size_t)V_ * 1024 * 2;

  // Input projections (gather fused; f64-exact accumulate, f32 storage)
  dgemm_embed<<<(2048 / 64) * (H_ / 64), 256, 0, stream>>>(src, encE, WihE, bihE,
                                                           x_e, 2048, H_, E_);
  dgemm_embed<<<(2048 / 64) * (H_ / 64), 256, 0, stream>>>(tgt, decE, WihD, bihD,
                                                           x_d, 2048, H_, E_);

  // Pre-transpose recurrence weights: WhhT[j][k]
  transpose_f32<<<dim3(H_ / 64, H_ / 64), 256, 0, stream>>>(WhhE, WhhTe, H_, H_);
  transpose_f32<<<dim3(H_ / 64, H_ / 64), 256, 0, stream>>>(WhhD, WhhTd, H_, H_);

  // Persistent group-local scan (8 independent 4-batch chains)
  hipMemsetAsync(h0, 0, 32 * 1024 * 4, stream);
  hipMemsetAsync(bar, 0, 8 * 32 * 4, stream);
  rnn_scan_grp2<<<256, 512, 0, stream>>>(x_e, x_d, WhhTe, WhhTd, bhhE, bhhD,
                                         h0, h1, hsb, bar);

  // Logits: out[b][t][:] = hs[t*B+b] @ Wout + bout  (bf16 MFMA, raw logits)
  transpose_bf16<<<dim3(H_ / 64, V_ / 64), 256, 0, stream>>>(Wout, WoutT, H_, V_);
  gemm_bt_swap<<<(2048 / 128) * (V_ / 128), 256, 0, stream>>>(hsb, WoutT, bout, out,
                                                              2048, V_, H_);
  // In-place log-softmax
  log_softmax_rows<<<B_ * T_, 1024, 0, stream>>>(out);
}

// Round 17
// 973.712 us; speedup vs baseline: 1.7329x; 1.0492x over previous
//
#include <hip/hip_runtime.h>
#include <hip/hip_bf16.h>
#include <math.h>

#define B_ 32
#define S_ 64
#define T_ 64
#define V_ 32000
#define E_ 512
#define H_ 1024

typedef __attribute__((ext_vector_type(8))) short short8;
typedef __attribute__((ext_vector_type(4))) float f32x4;

static __device__ __forceinline__ unsigned short f2bf(float f) {
  union { float f; unsigned u; } c; c.f = f;
  unsigned r = (c.u + 0x7fffu + ((c.u >> 16) & 1u)) >> 16;  // RNE
  return (unsigned short)r;
}

// ---------- fused embed + f64-accumulate GEMM, BOTH problems in one launch ----------
// half 0: C0 = emb0[idx0[m]] @ B0 + bias0 ; half 1: likewise. Internals
// identical to r16's dgemm_embed -> bit-identical x_e/x_d.
__global__ __launch_bounds__(256)
void dgemm_embed_dual(const int* __restrict__ idx0, const float* __restrict__ emb0,
                      const float* __restrict__ B0, const float* __restrict__ bias0,
                      float* __restrict__ C0,
                      const int* __restrict__ idx1, const float* __restrict__ emb1,
                      const float* __restrict__ B1, const float* __restrict__ bias1,
                      float* __restrict__ C1, int M, int N, int K) {
  const int half = blockIdx.x >> 9;
  const int bid = blockIdx.x & 511;
  const int* __restrict__ idx = half ? idx1 : idx0;
  const float* __restrict__ emb = half ? emb1 : emb0;
  const float* __restrict__ B = half ? B1 : B0;
  const float* __restrict__ bias = half ? bias1 : bias0;
  float* __restrict__ C = half ? C1 : C0;

  __shared__ float As[32][68];  // [k][m], padded to 16B multiple
  __shared__ float Bs[32][64];  // [k][n]
  const int nbm = M >> 6;
  const int bm = bid % nbm;
  const int bn = bid / nbm;
  const int tid = threadIdx.x;
  const int tr = tid >> 4, tc = tid & 15;

  const int arow = tid >> 3, acol = (tid & 7) * 4;
  const float* arp[2];
#pragma unroll
  for (int p = 0; p < 2; ++p) {
    int r = arow + p * 32;
    arp[p] = emb + (size_t)idx[bm * 64 + r] * E_;
  }

  double acc[4][4] = {};

  for (int kt = 0; kt < K; kt += 32) {
    {
#pragma unroll
      for (int p = 0; p < 2; ++p) {
        int r = arow + p * 32;
        float4 v = *(const float4*)(arp[p] + kt + acol);
        As[acol + 0][r] = v.x; As[acol + 1][r] = v.y;
        As[acol + 2][r] = v.z; As[acol + 3][r] = v.w;
      }
      int brow = tid >> 4, bcol = (tid & 15) * 4;
#pragma unroll
      for (int p = 0; p < 2; ++p) {
        int r = brow + p * 16;
        float4 v = *(const float4*)(B + (size_t)(kt + r) * N + bn * 64 + bcol);
        *(float4*)(&Bs[r][bcol]) = v;
      }
    }
    __syncthreads();
#pragma unroll
    for (int k = 0; k < 32; ++k) {
      float4 av = *(const float4*)(&As[k][tr * 4]);
      float4 bv = *(const float4*)(&Bs[k][tc * 4]);
      double a[4] = {(double)av.x, (double)av.y, (double)av.z, (double)av.w};
      double b[4] = {(double)bv.x, (double)bv.y, (double)bv.z, (double)bv.w};
#pragma unroll
      for (int i = 0; i < 4; ++i)
#pragma unroll
        for (int j = 0; j < 4; ++j) acc[i][j] = fma(a[i], b[j], acc[i][j]);
    }
    __syncthreads();
  }
#pragma unroll
  for (int i = 0; i < 4; ++i) {
    int gm = bm * 64 + tr * 4 + i;
    int gn = bn * 64 + tc * 4;
    float4 o;
    o.x = (float)(acc[i][0] + (double)bias[gn + 0]);
    o.y = (float)(acc[i][1] + (double)bias[gn + 1]);
    o.z = (float)(acc[i][2] + (double)bias[gn + 2]);
    o.w = (float)(acc[i][3] + (double)bias[gn + 3]);
    *(float4*)(C + (size_t)gm * N + gn) = o;
  }
}

// ---------- transpose fp32 [K][N] -> fp32 [N][K], both Whh in one launch ----------
__global__ __launch_bounds__(256)
void transpose_f32_dual(const float* __restrict__ W0, float* __restrict__ WT0,
                        const float* __restrict__ W1, float* __restrict__ WT1,
                        int K, int N) {
  const int half = blockIdx.y >> 4;
  const int by = blockIdx.y & 15;
  const float* __restrict__ W = half ? W1 : W0;
  float* __restrict__ WT = half ? WT1 : WT0;
  __shared__ float t[64][65];
  int k0 = blockIdx.x * 64;
  int n0 = by * 64;
  int tid = threadIdx.x;
  int r = tid >> 4, c4 = tid & 15;
#pragma unroll
  for (int i = 0; i < 4; ++i) {
    int row = r + i * 16;
    float4 v = *(const float4*)(W + (size_t)(k0 + row) * N + n0 + c4 * 4);
    t[row][c4 * 4 + 0] = v.x; t[row][c4 * 4 + 1] = v.y;
    t[row][c4 * 4 + 2] = v.z; t[row][c4 * 4 + 3] = v.w;
  }
  __syncthreads();
#pragma unroll
  for (int i = 0; i < 4; ++i) {
    int n = r + i * 16;
    float4 o;
    o.x = t[c4 * 4 + 0][n]; o.y = t[c4 * 4 + 1][n];
    o.z = t[c4 * 4 + 2][n]; o.w = t[c4 * 4 + 3][n];
    *(float4*)(WT + (size_t)(n0 + n) * K + k0 + c4 * 4) = o;
  }
}

// ---------- transpose fp32 [K][N] -> bf16 [N][K] ----------
__global__ __launch_bounds__(256)
void transpose_bf16(const float* __restrict__ W, unsigned short* __restrict__ WT,
                    int K, int N) {
  __shared__ float t[64][65];
  int k0 = blockIdx.x * 64;
  int n0 = blockIdx.y * 64;
  int tid = threadIdx.x;
  int r = tid >> 4, c4 = tid & 15;
#pragma unroll
  for (int i = 0; i < 4; ++i) {
    int row = r + i * 16;
    float4 v = *(const float4*)(W + (size_t)(k0 + row) * N + n0 + c4 * 4);
    t[row][c4 * 4 + 0] = v.x; t[row][c4 * 4 + 1] = v.y;
    t[row][c4 * 4 + 2] = v.z; t[row][c4 * 4 + 3] = v.w;
  }
  __syncthreads();
#pragma unroll
  for (int i = 0; i < 4; ++i) {
    int n = r + i * 16;
    ushort4 o;
    o.x = f2bf(t[c4 * 4 + 0][n]); o.y = f2bf(t[c4 * 4 + 1][n]);
    o.z = f2bf(t[c4 * 4 + 2][n]); o.w = f2bf(t[c4 * 4 + 3][n]);
    *(ushort4*)(WT + (size_t)(n0 + n) * K + k0 + c4 * 4) = o;
  }
}

// ---------- bf16 MFMA GEMM: C[M,N] = A[M,K] * BT[N,K]^T + bias ----------
// 128x128 tile, XOR-swizzled LDS, XCD swizzle, T14 reg-prefetch (r16 proven)
// + LDS-staged COALESCED epilogue: per mi-stripe, stage 32x128 f32 in dead
// staging LDS (stride 132 -> conflict-free writes) then NT-write 512B rows
// (was: 4x64B scattered segments/instr -> 314MB WRITE_SIZE, ~50% HBM eff).
__global__ __launch_bounds__(256)
void gemm_bt_swap(const unsigned short* __restrict__ A, const unsigned short* __restrict__ BT,
                  const float* __restrict__ bias, float* __restrict__ C,
                  int M, int N, int K) {
  __shared__ unsigned short AsBs[2][128 * 64];  // contiguous; reused by epilogue
  unsigned short* As = AsBs[0];
  unsigned short* Bs = AsBs[1];
  const int nbm = M >> 7;
  int idx = blockIdx.x;
  const int cpx = gridDim.x >> 3;
  idx = (idx & 7) * cpx + (idx >> 3);
  const int bm = idx % nbm;
  const int bn = idx / nbm;
  const int tid = threadIdx.x;
  const int lane = tid & 63;
  const int wr = (tid >> 6) >> 1;
  const int wc = (tid >> 6) & 1;

  f32x4 acc[4][4] = {};

  int srow[4], scol8[4], ssw[4];
#pragma unroll
  for (int i = 0; i < 4; ++i) {
    int c = i * 256 + tid;
    srow[i] = c >> 3; scol8[i] = c & 7;
    ssw[i] = scol8[i] ^ (srow[i] & 7);
  }

  short8 av[4], bv[4];
#pragma unroll
  for (int i = 0; i < 4; ++i) {
    av[i] = *(const short8*)(A + (size_t)(bm * 128 + srow[i]) * K + scol8[i] * 8);
    bv[i] = *(const short8*)(BT + (size_t)(bn * 128 + srow[i]) * K + scol8[i] * 8);
  }

  for (int kt = 0; kt < K; kt += 64) {
#pragma unroll
    for (int i = 0; i < 4; ++i) {
      *(short8*)(As + srow[i] * 64 + ssw[i] * 8) = av[i];
      *(short8*)(Bs + srow[i] * 64 + ssw[i] * 8) = bv[i];
    }
    __syncthreads();

    if (kt + 64 < K) {
#pragma unroll
      for (int i = 0; i < 4; ++i) {
        av[i] = *(const short8*)(A + (size_t)(bm * 128 + srow[i]) * K + kt + 64 + scol8[i] * 8);
        bv[i] = *(const short8*)(BT + (size_t)(bn * 128 + srow[i]) * K + kt + 64 + scol8[i] * 8);
      }
    }

#pragma unroll
    for (int kk = 0; kk < 64; kk += 32) {
      int kc = (kk + ((lane >> 4) << 3)) >> 3;
      short8 af[4], bfr[4];
#pragma unroll
      for (int mi = 0; mi < 4; ++mi) {
        int row = wr * 64 + mi * 16 + (lane & 15);
        af[mi] = *(const short8*)(As + row * 64 + ((kc ^ (row & 7)) << 3));
      }
#pragma unroll
      for (int ni = 0; ni < 4; ++ni) {
        int row = wc * 64 + ni * 16 + (lane & 15);
        bfr[ni] = *(const short8*)(Bs + row * 64 + ((kc ^ (row & 7)) << 3));
      }
#pragma unroll
      for (int mi = 0; mi < 4; ++mi)
#pragma unroll
        for (int ni = 0; ni < 4; ++ni)
          acc[mi][ni] = __builtin_amdgcn_mfma_f32_16x16x32_bf16(
              af[mi], bfr[ni], acc[mi][ni], 0, 0, 0);
    }
    __syncthreads();
  }

  // ---- coalesced epilogue (values bit-identical: same acc+bias floats) ----
  float* Ct = (float*)AsBs;  // 32 x 132 f32 = 16.9 KB (staging LDS is dead)
  const int cq = (lane >> 4) << 2;  // C/D: row = cq+q, col = cn
  const int cn = lane & 15;
#pragma unroll
  for (int mi = 0; mi < 4; ++mi) {
    if (mi) __syncthreads();  // prev write-out readers done
#pragma unroll
    for (int ni = 0; ni < 4; ++ni) {
      int gn = bn * 128 + wc * 64 + ni * 16 + cn;
      float bvv = bias[gn];
#pragma unroll
      for (int q = 0; q < 4; ++q)
        Ct[(wr * 16 + cq + q) * 132 + wc * 64 + ni * 16 + cn] =
            acc[mi][ni][q] + bvv;
    }
    __syncthreads();
    // write-out: 1024 float4 in 4 passes; each wave-instr = 2 x 512B rows
#pragma unroll
    for (int p = 0; p < 4; ++p) {
      int f = p * 256 + tid;
      int r = f >> 5, c4 = f & 31;
      float4 v = *(const float4*)(Ct + r * 132 + c4 * 4);
      int gm = bm * 128 + (r >> 4) * 64 + mi * 16 + (r & 15);
      int b = gm & (B_ - 1);
      int t = gm >> 5;
      float* dstp = &C[((size_t)b * T_ + t) * N + bn * 128 + c4 * 4];
      __builtin_nontemporal_store(v.x, dstp + 0);
      __builtin_nontemporal_store(v.y, dstp + 1);
      __builtin_nontemporal_store(v.z, dstp + 2);
      __builtin_nontemporal_store(v.w, dstp + 3);
    }
  }
}

// ---------- persistent group-local RNN scan (r12/r16 proven form, FROZEN) ----------
__global__ __launch_bounds__(512)
void rnn_scan_grp2(const float* __restrict__ xe, const float* __restrict__ xd,
                   const float* __restrict__ WTe, const float* __restrict__ WTd,
                   const float* __restrict__ bhhE, const float* __restrict__ bhhD,
                   float* __restrict__ hA, float* __restrict__ hB,
                   unsigned short* __restrict__ hsb, unsigned* __restrict__ bar) {
  __shared__ float hl[4 * 1024];  // 16 KB chain h-slice
  const int tid = threadIdx.x;
  const int grp = blockIdx.x & 7;
  const int jslot = blockIdx.x >> 3;
  const int jbase = jslot * 32;
  const int bg = grp * 4;
  const int w = tid >> 6;  // wave -> j-quad
  const int l = tid & 63;  // k-split lane
  unsigned* mybar = bar + grp * 32;  // 128B-spaced counters

  const int a = 8 * (l & 1) + 4 * ((l >> 1) & 1) + 2 * ((l >> 2) & 1) +
                ((l >> 3) & 1);
  const int lb = a >> 2;
  const int gb = bg + lb;
  const int gj = jbase + w * 4 + (a & 3);
  const float bje = bhhE[gj];
  const float bjd = bhhD[gj];

  float4 wreg[4][4];
  {
    const float* wsrc = WTe + (size_t)(jbase + w * 4) * 1024;
#pragma unroll
    for (int i = 0; i < 4; ++i) {
      int g = l + 64 * i;
#pragma unroll
      for (int ji = 0; ji < 4; ++ji)
        wreg[i][ji] = *(const float4*)(wsrc + (size_t)ji * 1024 + g * 4);
    }
  }

  for (int t = 0; t < 128; ++t) {
    if (t == 64) {
      const float* wsrc = WTd + (size_t)(jbase + w * 4) * 1024;
#pragma unroll
      for (int i = 0; i < 4; ++i) {
        int g = l + 64 * i;
#pragma unroll
        for (int ji = 0; ji < 4; ++ji)
          wreg[i][ji] = *(const float4*)(wsrc + (size_t)ji * 1024 + g * 4);
      }
    }
    const bool enc = (t < 64);
    const int s = t & 63;
    const float* __restrict__ h_in = (t & 1) ? hB : hA;
    float* __restrict__ h_out = (t & 1) ? hA : hB;
    const float* __restrict__ x = enc ? xe : xd;

    float xv = x[((size_t)gb * 64 + s) * H_ + gj];

    {
      const float* hsrc = h_in + bg * H_;
      float v[8];
#pragma unroll
      for (int u = 0; u < 8; ++u)
        v[u] = __hip_atomic_load(hsrc + u * 512 + tid, __ATOMIC_RELAXED,
                                 __HIP_MEMORY_SCOPE_AGENT);
#pragma unroll
      for (int u = 0; u < 8; ++u)
        hl[u * 512 + tid] = v[u];
    }
    __syncthreads();

    double acc[4][4];
#pragma unroll
    for (int bi = 0; bi < 4; ++bi)
#pragma unroll
      for (int ji = 0; ji < 4; ++ji) acc[bi][ji] = 0.;

#pragma unroll
    for (int i = 0; i < 4; ++i) {
      int g = l + 64 * i;
      float4 hv[4];
#pragma unroll
      for (int bi = 0; bi < 4; ++bi)
        hv[bi] = *(const float4*)(hl + bi * 1024 + g * 4);
#pragma unroll
      for (int bi = 0; bi < 4; ++bi)
#pragma unroll
        for (int ji = 0; ji < 4; ++ji) {
          acc[bi][ji] = fma((double)hv[bi].x, (double)wreg[i][ji].x, acc[bi][ji]);
          acc[bi][ji] = fma((double)hv[bi].y, (double)wreg[i][ji].y, acc[bi][ji]);
          acc[bi][ji] = fma((double)hv[bi].z, (double)wreg[i][ji].z, acc[bi][ji]);
          acc[bi][ji] = fma((double)hv[bi].w, (double)wreg[i][ji].w, acc[bi][ji]);
        }
    }

    double r8[8], r4[4], r2[2], r1;
#pragma unroll
    for (int aa = 0; aa < 8; ++aa) {
      double send = (l & 1) ? acc[aa >> 2][aa & 3] : acc[(aa + 8) >> 2][(aa + 8) & 3];
      double mine = (l & 1) ? acc[(aa + 8) >> 2][(aa + 8) & 3] : acc[aa >> 2][aa & 3];
      r8[aa] = mine + __shfl_xor(send, 1);
    }
#pragma unroll
    for (int aa = 0; aa < 4; ++aa) {
      double send = (l & 2) ? r8[aa] : r8[aa + 4];
      double mine = (l & 2) ? r8[aa + 4] : r8[aa];
      r4[aa] = mine + __shfl_xor(send, 2);
    }
#pragma unroll
    for (int aa = 0; aa < 2; ++aa) {
      double send = (l & 4) ? r4[aa] : r4[aa + 2];
      double mine = (l & 4) ? r4[aa + 2] : r4[aa];
      r2[aa] = mine + __shfl_xor(send, 4);
    }
    {
      double send = (l & 8) ? r2[0] : r2[1];
      double mine = (l & 8) ? r2[1] : r2[0];
      r1 = mine + __shfl_xor(send, 8);
    }
    r1 += __shfl_xor(r1, 16);
    r1 += __shfl_xor(r1, 32);

    float hf = 0.f;
    if (l < 16) {
      double v = r1 + (double)xv + (double)(enc ? bje : bjd);
      double h = tanh(v);
      hf = (float)h;
      __hip_atomic_store(&h_out[(size_t)gb * H_ + gj], hf, __ATOMIC_RELAXED,
                         __HIP_MEMORY_SCOPE_AGENT);
    }

    if (t < 127) {
      asm volatile("s_waitcnt vmcnt(0)" ::: "memory");
      __syncthreads();
      if (tid == 0) {
        __hip_atomic_fetch_add(mybar, 1u, __ATOMIC_RELAXED,
                               __HIP_MEMORY_SCOPE_AGENT);
        unsigned tgt = 32u * (unsigned)(t + 1);
        while (__hip_atomic_load(mybar, __ATOMIC_RELAXED,
                                 __HIP_MEMORY_SCOPE_AGENT) < tgt)
          __builtin_amdgcn_s_sleep(1);
      }
      __syncthreads();
    }
    if (!enc && l < 16)
      __builtin_nontemporal_store(f2bf(hf),
                                  &hsb[(size_t)s * (B_ * H_) + (size_t)gb * H_ + gj]);
  }
}

// ---------- log-softmax, row staged in LDS (one HBM read + one write) ----------
__global__ __launch_bounds__(1024)
void log_softmax_rows(float* __restrict__ out) {
  __shared__ float rl[32000];  // 125 KB row stage
  __shared__ float wm[16], wsv[16];
  float* row = out + (size_t)blockIdx.x * V_;
  const int tid = threadIdx.x;
  float m = -INFINITY, s = 0.f;
  for (int i = tid; i < V_ / 4; i += 1024) {
    float4 v = *(const float4*)(row + i * 4);
    *(float4*)(rl + i * 4) = v;
    float mx = fmaxf(fmaxf(v.x, v.y), fmaxf(v.z, v.w));
    if (mx > m) { s *= __expf(m - mx); m = mx; }
    s += __expf(v.x - m) + __expf(v.y - m) + __expf(v.z - m) + __expf(v.w - m);
  }
#pragma unroll
  for (int o = 32; o; o >>= 1) {
    float mo = __shfl_xor(m, o);
    float so = __shfl_xor(s, o);
    float mn = fmaxf(m, mo);
    s = s * __expf(m - mn) + so * __expf(mo - mn);
    m = mn;
  }
  int wv = tid >> 6;
  if ((tid & 63) == 0) { wm[wv] = m; wsv[wv] = s; }
  __syncthreads();
  float M = wm[0];
#pragma unroll
  for (int i = 1; i < 16; ++i) M = fmaxf(M, wm[i]);
  float Ssum = 0.f;
#pragma unroll
  for (int i = 0; i < 16; ++i) Ssum += wsv[i] * __expf(wm[i] - M);
  float L = M + logf(Ssum);
  for (int i = tid; i < V_ / 4; i += 1024) {
    float4 v = *(const float4*)(rl + i * 4);
    v.x -= L; v.y -= L; v.z -= L; v.w -= L;
    __builtin_nontemporal_store(v.x, &row[i * 4 + 0]);
    __builtin_nontemporal_store(v.y, &row[i * 4 + 1]);
    __builtin_nontemporal_store(v.z, &row[i * 4 + 2]);
    __builtin_nontemporal_store(v.w, &row[i * 4 + 3]);
  }
}

extern "C" void kernel_launch(void* const* d_in, const int* in_sizes, int n_in,
                              void* d_out, int out_size, void* d_ws, size_t ws_size,
                              hipStream_t stream) {
  const int*   src  = (const int*)  d_in[0];
  const int*   tgt  = (const int*)  d_in[1];
  const float* encE = (const float*)d_in[2];
  const float* decE = (const float*)d_in[3];
  const float* WihE = (const float*)d_in[4];
  const float* bihE = (const float*)d_in[5];
  const float* WhhE = (const float*)d_in[6];
  const float* bhhE = (const float*)d_in[7];
  const float* WihD = (const float*)d_in[8];
  const float* bihD = (const float*)d_in[9];
  const float* WhhD = (const float*)d_in[10];
  const float* bhhD = (const float*)d_in[11];
  const float* Wout = (const float*)d_in[12];
  const float* bout = (const float*)d_in[13];
  float* out = (float*)d_out;

  char* w = (char*)d_ws;
  float* x_e = (float*)w;                      w += (size_t)2048 * 1024 * 4;
  float* x_d = (float*)w;                      w += (size_t)2048 * 1024 * 4;
  float* h0  = (float*)w;                      w += 32 * 1024 * 4;
  float* h1  = (float*)w;                      w += 32 * 1024 * 4;
  unsigned* bar = (unsigned*)w;                w += 8 * 32 * 4;  // 8 counters, 128B apart
  float* WhhTe = (float*)w;                    w += (size_t)1024 * 1024 * 4;
  float* WhhTd = (float*)w;                    w += (size_t)1024 * 1024 * 4;
  unsigned short* hsb   = (unsigned short*)w;  w += (size_t)2048 * 1024 * 2;
  unsigned short* WoutT = (unsigned short*)w;  w += (size_t)V_ * 1024 * 2;

  // Input projections, both problems fused into one launch
  dgemm_embed_dual<<<1024, 256, 0, stream>>>(src, encE, WihE, bihE, x_e,
                                             tgt, decE, WihD, bihD, x_d,
                                             2048, H_, E_);

  // Pre-transpose both recurrence weight matrices in one launch
  transpose_f32_dual<<<dim3(H_ / 64, 2 * (H_ / 64)), 256, 0, stream>>>(
      WhhE, WhhTe, WhhD, WhhTd, H_, H_);

  // Persistent group-local scan (8 independent 4-batch chains)
  hipMemsetAsync(h0, 0, 32 * 1024 * 4, stream);
  hipMemsetAsync(bar, 0, 8 * 32 * 4, stream);
  rnn_scan_grp2<<<256, 512, 0, stream>>>(x_e, x_d, WhhTe, WhhTd, bhhE, bhhD,
                                         h0, h1, hsb, bar);

  // Logits: out[b][t][:] = hs[t*B+b] @ Wout + bout  (bf16 MFMA, raw logits)
  transpose_bf16<<<dim3(H_ / 64, V_ / 64), 256, 0, stream>>>(Wout, WoutT, H_, V_);
  gemm_bt_swap<<<(2048 / 128) * (V_ / 128), 256, 0, stream>>>(hsb, WoutT, bout, out,
                                                              2048, V_, H_);
  // In-place log-softmax
  log_softmax_rows<<<B_ * T_, 1024, 0, stream>>>(out);
}